// Round 13
// baseline (484.941 us; speedup 1.0000x reference)
//
#include <hip/hip_runtime.h>

// GRU last-hidden: B=1024, C=64, T=1024, H=32, G=96, fp32.
// x:(B,64,1024) W_ih:(96,64) W_hh:(96,32) b_ih,b_hh:(96) out:(B,32)
//
// 256 blocks x 384 threads (6 waves); block = 4 batches:
//   waves 0-3 = producers: gx tile (32t x 96g) via MFMA bf16 hi/lo 3-product
//     (R9 register-squeezed + R11 xs swizzle — byte-identical to R11).
//   waves 4-5 = consumers, TWO batches per wave (wave4: b0,b1; wave5: b2,b3):
//     R13 insight: a wave issues in-order, so one serial GRU chain alternates
//     issue with dependency stalls (R11: 590cy/step, VALUBusy 66% -> 34% dead
//     cycles). The 4 batches/CU are INDEPENDENT chains; interleaving 2 chains
//     in one wave lets chain B's issue fill chain A's stalls. Weights are
//     batch-shared (64 VGPR, same as R11); only ~13 extra state regs.
//     Matvec = R8/R10-verified scalar readlane->v_fmac (SGPR operand), no
//     pk-movs, no dot2 (R12's fdot2/fallback regressed).
//
// LDS (157056 B): unchanged from R11.

typedef short bf16x8 __attribute__((ext_vector_type(8)));
typedef float f32x4  __attribute__((ext_vector_type(4)));

#define TT 32
#define GXS 97
#define LDS_BYTES 157056

#define GLL16(gp, lp)                                                        \
  __builtin_amdgcn_global_load_lds(                                          \
      (const __attribute__((address_space(1))) void*)(gp),                   \
      (__attribute__((address_space(3))) void*)(lp), 16, 0, 0)

static __device__ __forceinline__ short f2bf(float f) {   // RNE float->bf16
    unsigned u = __float_as_uint(f);
    u += 0x7fffu + ((u >> 16) & 1u);
    return (short)(u >> 16);
}
static __device__ __forceinline__ float bf2f(short s) {
    return __uint_as_float(((unsigned)(unsigned short)s) << 16);
}
static __device__ __forceinline__ float rlane(int v, int j) {
    return __int_as_float(__builtin_amdgcn_readlane(v, j));
}

__global__ __launch_bounds__(384) void gru_fused13(
    const float* __restrict__ x,
    const float* __restrict__ W_ih,
    const float* __restrict__ W_hh,
    const float* __restrict__ b_ih,
    const float* __restrict__ b_hh,
    float* __restrict__ out)
{
    extern __shared__ char smem[];
    short* wfH   = (short*)smem;                    // 768 frags * 8 shorts
    short* wfL   = (short*)(smem + 12288);
    float* xs    = (float*)(smem + 24576);          // 4 * 2048 floats
    float* gxs   = (float*)(smem + 57344);          // 2*4*32*97 floats
    float* biasc = (float*)(smem + 156672);         // 96 floats

    const int tid  = threadIdx.x;
    const int wid  = tid >> 6;
    const int lane = tid & 63;
    const int bid  = blockIdx.x;

    // ---- one-time: W_ih -> bf16 hi/lo MFMA B-fragments in LDS ----
    for (int f = tid; f < 768; f += 384) {
        int slot = f & 63, ktnt = f >> 6;
        int kt = ktnt / 6, nt = ktnt - kt * 6;
        int g  = nt * 16 + (slot & 15);
        int c0 = kt * 32 + (slot >> 4) * 8;
        const float* wr = W_ih + g * 64 + c0;
        bf16x8 hi, lo;
        #pragma unroll
        for (int j = 0; j < 8; ++j) {
            float v  = wr[j];
            short hb = f2bf(v);
            hi[j] = hb;
            lo[j] = f2bf(v - bf2f(hb));
        }
        *(bf16x8*)(wfH + f * 8) = hi;
        *(bf16x8*)(wfL + f * 8) = lo;
    }
    if (tid < 96) biasc[tid] = b_ih[tid] + (tid < 64 ? b_hh[tid] : 0.f);

    // ================= producer state =================
    const float* xb = nullptr;
    if (wid < 4) xb = x + (size_t)(bid * 4 + wid) * 64 * 1024;

    // ========== consumer state (gate-split, R8-verified layout) ==========
    const int h  = lane & 31;
    const int h3 = h * 3;
    float wg_[32], wn_[32];     // wg_: r-row (half0) / z-row (half1); wn_: n-row
    float bhn = 0.f, houtA = 0.f, houtB = 0.f;
    if (wid >= 4) {
        const int grow = (lane < 32) ? h : (32 + h);
        #pragma unroll
        for (int j = 0; j < 32; ++j) {
            wg_[j] = W_hh[grow * 32 + j];
            wn_[j] = W_hh[(64 + h) * 32 + j];
        }
        bhn = b_hh[64 + h];
    }

    // async x-tile: LDS[c][q] holds x[c][q ^ (((c>>3)&3)<<3)] (XOR applied
    // to the GLOBAL source t-offset; LDS dest stays linear).
    auto load_xtile = [&](int tile) {
        const int tbase = tile * TT;
        const int c_lo  = lane >> 3;
        #pragma unroll
        for (int i = 0; i < 8; ++i) {
            const int toff = (((lane & 7) << 2) ^ ((i & 3) << 3));
            const float* gp = xb + (i * 8 + c_lo) * 1024 + tbase + toff;
            float* lp = xs + wid * 2048 + i * 256;   // wave-uniform base
            GLL16(gp, lp);
        }
    };

    // producer: gx tile via MFMA, mt-at-a-time, paired B-frags, bias from LDS
    auto stage1 = [&](int buf, int prefetch_tile) {
        float* gb = gxs + buf * 12416 + wid * 3104;
        #pragma unroll
        for (int mt = 0; mt < 2; ++mt) {
            bf16x8 ah[2], al[2];
            const int tS = (mt * 16 + (lane & 15)) ^ ((lane >> 4) << 3);
            #pragma unroll
            for (int kt = 0; kt < 2; ++kt) {
                const int cb = kt * 32 + (lane >> 4) * 8;
                float xf[8];
                #pragma unroll
                for (int j = 0; j < 8; ++j)
                    xf[j] = xs[wid * 2048 + (cb + j) * 32 + tS];
                #pragma unroll
                for (int j = 0; j < 8; ++j) {
                    short hb_ = f2bf(xf[j]);
                    ah[kt][j] = hb_;
                    al[kt][j] = f2bf(xf[j] - bf2f(hb_));
                }
            }
            const int row0 = mt * 16 + ((lane >> 4) << 2);
            #pragma unroll
            for (int nt = 0; nt < 6; ++nt) {
                const int g   = nt * 16 + (lane & 15);
                const int off = (g & 31) * 3 + (g >> 5);   // packed column
                const float bias = biasc[g];
                f32x4 acc = {bias, bias, bias, bias};
                bf16x8 b0 = *(const bf16x8*)(wfH + ((nt)     * 64 + lane) * 8);
                bf16x8 b1 = *(const bf16x8*)(wfH + ((6 + nt) * 64 + lane) * 8);
                acc = __builtin_amdgcn_mfma_f32_16x16x32_bf16(ah[0], b0, acc, 0, 0, 0);
                acc = __builtin_amdgcn_mfma_f32_16x16x32_bf16(ah[1], b1, acc, 0, 0, 0);
                acc = __builtin_amdgcn_mfma_f32_16x16x32_bf16(al[0], b0, acc, 0, 0, 0);
                acc = __builtin_amdgcn_mfma_f32_16x16x32_bf16(al[1], b1, acc, 0, 0, 0);
                b0 = *(const bf16x8*)(wfL + ((nt)     * 64 + lane) * 8);
                b1 = *(const bf16x8*)(wfL + ((6 + nt) * 64 + lane) * 8);
                acc = __builtin_amdgcn_mfma_f32_16x16x32_bf16(ah[0], b0, acc, 0, 0, 0);
                acc = __builtin_amdgcn_mfma_f32_16x16x32_bf16(ah[1], b1, acc, 0, 0, 0);
                // C layout: col = lane&15 (g), row = (lane>>4)*4 + reg (t)
                #pragma unroll
                for (int j = 0; j < 4; ++j)
                    gb[(row0 + j) * GXS + off] = acc[j];
            }
            if (mt == 0) __builtin_amdgcn_sched_barrier(0);  // cap reg pressure
        }
        // all xs reads drained -> safe to overwrite own xs region
        asm volatile("s_waitcnt lgkmcnt(0)" ::: "memory");
        if (prefetch_tile >= 0) load_xtile(prefetch_tile);
    };

    // consumer: 32 steps x TWO interleaved batch chains. Per batch-step:
    // 32 readlane + 64 scalar fmac + 1 shfl + joint sigmoid. The two chains'
    // independent instructions fill each other's dependency stalls.
    auto stage2 = [&](int buf) {
        const int bp = (wid - 4) * 2;
        const float* gA = gxs + buf * 12416 + bp * 3104;
        const float* gB = gA + 3104;
        __builtin_amdgcn_s_setprio(1);           // consumers own the SIMD
        float xrA = gA[h3], xzA = gA[h3 + 1], xnA = gA[h3 + 2];
        float xrB = gB[h3], xzB = gB[h3 + 1], xnB = gB[h3 + 2];
        #pragma unroll 2
        for (int s = 0; s < TT; ++s) {
            // prefetch step s+1 for both batches (off-chain)
            float xrAn = 0.f, xzAn = 0.f, xnAn = 0.f;
            float xrBn = 0.f, xzBn = 0.f, xnBn = 0.f;
            if (s < TT - 1) {
                const float* nA = gA + (s + 1) * GXS + h3;
                const float* nB = gB + (s + 1) * GXS + h3;
                xrAn = nA[0]; xzAn = nA[1]; xnAn = nA[2];
                xrBn = nB[0]; xzBn = nB[1]; xnBn = nB[2];
            }
            // ---- matvec A ----
            const int hbA = __float_as_int(houtA);
            float aA0 = 0.f, aA1 = 0.f, aA2 = 0.f, aA3 = 0.f;
            float nA0 = 0.f, nA1 = 0.f, nA2 = 0.f, nA3 = 0.f;
            #pragma unroll
            for (int j = 0; j < 32; j += 4) {
                float s0 = rlane(hbA, j),     s1 = rlane(hbA, j + 1);
                float s2 = rlane(hbA, j + 2), s3 = rlane(hbA, j + 3);
                aA0 = fmaf(wg_[j],     s0, aA0);
                aA1 = fmaf(wg_[j + 1], s1, aA1);
                aA2 = fmaf(wg_[j + 2], s2, aA2);
                aA3 = fmaf(wg_[j + 3], s3, aA3);
                nA0 = fmaf(wn_[j],     s0, nA0);
                nA1 = fmaf(wn_[j + 1], s1, nA1);
                nA2 = fmaf(wn_[j + 2], s2, nA2);
                nA3 = fmaf(wn_[j + 3], s3, nA3);
            }
            // ---- matvec B (independent; fills A's stalls) ----
            const int hbB = __float_as_int(houtB);
            float aB0 = 0.f, aB1 = 0.f, aB2 = 0.f, aB3 = 0.f;
            float nB0 = 0.f, nB1 = 0.f, nB2 = 0.f, nB3 = 0.f;
            #pragma unroll
            for (int j = 0; j < 32; j += 4) {
                float s0 = rlane(hbB, j),     s1 = rlane(hbB, j + 1);
                float s2 = rlane(hbB, j + 2), s3 = rlane(hbB, j + 3);
                aB0 = fmaf(wg_[j],     s0, aB0);
                aB1 = fmaf(wg_[j + 1], s1, aB1);
                aB2 = fmaf(wg_[j + 2], s2, aB2);
                aB3 = fmaf(wg_[j + 3], s3, aB3);
                nB0 = fmaf(wn_[j],     s0, nB0);
                nB1 = fmaf(wn_[j + 1], s1, nB1);
                nB2 = fmaf(wn_[j + 2], s2, nB2);
                nB3 = fmaf(wn_[j + 3], s3, nB3);
            }
            // ---- finish A & B (sigmoids + shfls overlap each other) ----
            float accAA = (aA0 + aA1) + (aA2 + aA3);
            float accNA = (nA0 + nA1) + (nA2 + nA3);
            float accAB = (aB0 + aB1) + (aB2 + aB3);
            float accNB = (nB0 + nB1) + (nB2 + nB3);
            float xgA  = (lane < 32) ? xrA : xzA;
            float xgB  = (lane < 32) ? xrB : xzB;
            float sigA = __builtin_amdgcn_rcpf(1.f + __expf(-(xgA + accAA)));
            float sigB = __builtin_amdgcn_rcpf(1.f + __expf(-(xgB + accAB)));
            float zsA  = __shfl_xor(sigA, 32, 64);   // half0 receives z
            float zsB  = __shfl_xor(sigB, 32, 64);
            if (lane < 32) {
                float nxA = fmaf(sigA, accNA + bhn, xnA);   // sigA == r
                float nA  = 1.f - 2.f * __builtin_amdgcn_rcpf(__expf(2.f * nxA) + 1.f);
                houtA = nA + zsA * (houtA - nA);
                float nxB = fmaf(sigB, accNB + bhn, xnB);
                float nB  = 1.f - 2.f * __builtin_amdgcn_rcpf(__expf(2.f * nxB) + 1.f);
                houtB = nB + zsB * (houtB - nB);
            }
            xrA = xrAn; xzA = xzAn; xnA = xnAn;
            xrB = xrBn; xzB = xzBn; xnB = xnBn;
        }
        __builtin_amdgcn_s_setprio(0);
    };

    // ================= pipeline =================
    if (wid < 4) load_xtile(0);
    __syncthreads();                    // wfrag+bias ready; xs = tile 0

    if (wid < 4) stage1(0, 1);          // gxs[0] = tile 0; prefetch tile 1
    __syncthreads();                    // gxs[0] visible; xs = tile 1

    for (int k = 0; k < 32; ++k) {
        if (wid >= 4) {
            stage2(k & 1);
        } else if (k < 31) {
            stage1((k + 1) & 1, (k < 30) ? (k + 2) : -1);
        }
        __syncthreads();
    }

    if (wid >= 4 && lane < 32) {
        const int bp = (wid - 4) * 2;
        out[(bid * 4 + bp)     * 32 + h] = houtA;
        out[(bid * 4 + bp + 1) * 32 + h] = houtB;
    }
}

extern "C" void kernel_launch(void* const* d_in, const int* in_sizes, int n_in,
                              void* d_out, int out_size, void* d_ws, size_t ws_size,
                              hipStream_t stream) {
    const float* x    = (const float*)d_in[0];
    const float* W_ih = (const float*)d_in[1];
    const float* W_hh = (const float*)d_in[2];
    const float* b_ih = (const float*)d_in[3];
    const float* b_hh = (const float*)d_in[4];
    float* out = (float*)d_out;

    hipFuncSetAttribute((const void*)gru_fused13,
                        hipFuncAttributeMaxDynamicSharedMemorySize, LDS_BYTES);
    gru_fused13<<<256, 384, LDS_BYTES, stream>>>(x, W_ih, W_hh, b_ih, b_hh, out);
}

// Round 14
// 278.696 us; speedup vs baseline: 1.7400x; 1.7400x over previous
//
#include <hip/hip_runtime.h>

// GRU last-hidden: B=1024, C=64, T=1024, H=32, G=96, fp32.
// x:(B,64,1024) W_ih:(96,64) W_hh:(96,32) b_ih,b_hh:(96) out:(B,32)
//
// 256 blocks x 512 threads; block = 4 batches, 8 waves:
//   waves 0-3 = producers: gx tile (32t x 96g) via MFMA bf16 hi/lo 3-product
//     (R9 register-squeezed + R11 xs swizzle — unchanged).
//   waves 4-7 = consumers (1 batch/wave — R13's 2-chains/wave doubled per-wave
//     issue and regressed 2x; reverted). R8-verified gate-split recurrence,
//     R14 chain reorder: R11 computed n-matvec BEFORE the shfl, so the
//     ds_bpermute latency (~120cy) sat idle on the serial chain. New order:
//       r/z matvec -> sigA -> issue shfl(sig) -> [sched_barrier pin] ->
//       n-matvec (32 rl + 32 fma issue ~128cy) UNDER the shfl -> tail.
//     Fresh readlanes in the n-loop (no cross-loop register array -> no
//     spill risk); readlane issue is hidden inside the shfl window.
//
// LDS (157056 B): unchanged from R11.

typedef short bf16x8 __attribute__((ext_vector_type(8)));
typedef float f32x4  __attribute__((ext_vector_type(4)));

#define TT 32
#define GXS 97
#define LDS_BYTES 157056

#define GLL16(gp, lp)                                                        \
  __builtin_amdgcn_global_load_lds(                                          \
      (const __attribute__((address_space(1))) void*)(gp),                   \
      (__attribute__((address_space(3))) void*)(lp), 16, 0, 0)

static __device__ __forceinline__ short f2bf(float f) {   // RNE float->bf16
    unsigned u = __float_as_uint(f);
    u += 0x7fffu + ((u >> 16) & 1u);
    return (short)(u >> 16);
}
static __device__ __forceinline__ float bf2f(short s) {
    return __uint_as_float(((unsigned)(unsigned short)s) << 16);
}
static __device__ __forceinline__ float rlane(int v, int j) {
    return __int_as_float(__builtin_amdgcn_readlane(v, j));
}

__global__ __launch_bounds__(512) void gru_fused14(
    const float* __restrict__ x,
    const float* __restrict__ W_ih,
    const float* __restrict__ W_hh,
    const float* __restrict__ b_ih,
    const float* __restrict__ b_hh,
    float* __restrict__ out)
{
    extern __shared__ char smem[];
    short* wfH   = (short*)smem;                    // 768 frags * 8 shorts
    short* wfL   = (short*)(smem + 12288);
    float* xs    = (float*)(smem + 24576);          // 4 * 2048 floats
    float* gxs   = (float*)(smem + 57344);          // 2*4*32*97 floats
    float* biasc = (float*)(smem + 156672);         // 96 floats

    const int tid  = threadIdx.x;
    const int wid  = tid >> 6;
    const int lane = tid & 63;
    const int bid  = blockIdx.x;

    // ---- one-time: W_ih -> bf16 hi/lo MFMA B-fragments in LDS ----
    for (int f = tid; f < 768; f += 512) {
        int slot = f & 63, ktnt = f >> 6;
        int kt = ktnt / 6, nt = ktnt - kt * 6;
        int g  = nt * 16 + (slot & 15);
        int c0 = kt * 32 + (slot >> 4) * 8;
        const float* wr = W_ih + g * 64 + c0;
        bf16x8 hi, lo;
        #pragma unroll
        for (int j = 0; j < 8; ++j) {
            float v  = wr[j];
            short hb = f2bf(v);
            hi[j] = hb;
            lo[j] = f2bf(v - bf2f(hb));
        }
        *(bf16x8*)(wfH + f * 8) = hi;
        *(bf16x8*)(wfL + f * 8) = lo;
    }
    if (tid < 96) biasc[tid] = b_ih[tid] + (tid < 64 ? b_hh[tid] : 0.f);

    // ================= producer state =================
    const float* xb = nullptr;
    if (wid < 4) xb = x + (size_t)(bid * 4 + wid) * 64 * 1024;

    // ========== consumer state (gate-split, R8-verified layout) ==========
    const int h  = lane & 31;
    const int h3 = h * 3;
    float wg_[32], wn_[32];     // wg_: r-row (half0) / z-row (half1); wn_: n-row
    float bhn = 0.f, hout = 0.f;
    if (wid >= 4) {
        const int grow = (lane < 32) ? h : (32 + h);
        #pragma unroll
        for (int j = 0; j < 32; ++j) {
            wg_[j] = W_hh[grow * 32 + j];
            wn_[j] = W_hh[(64 + h) * 32 + j];
        }
        bhn = b_hh[64 + h];
    }

    // async x-tile: LDS[c][q] holds x[c][q ^ (((c>>3)&3)<<3)] (XOR applied
    // to the GLOBAL source t-offset; LDS dest stays linear).
    auto load_xtile = [&](int tile) {
        const int tbase = tile * TT;
        const int c_lo  = lane >> 3;
        #pragma unroll
        for (int i = 0; i < 8; ++i) {
            const int toff = (((lane & 7) << 2) ^ ((i & 3) << 3));
            const float* gp = xb + (i * 8 + c_lo) * 1024 + tbase + toff;
            float* lp = xs + wid * 2048 + i * 256;   // wave-uniform base
            GLL16(gp, lp);
        }
    };

    // producer: gx tile via MFMA, mt-at-a-time, paired B-frags, bias from LDS
    auto stage1 = [&](int buf, int prefetch_tile) {
        float* gb = gxs + buf * 12416 + wid * 3104;
        #pragma unroll
        for (int mt = 0; mt < 2; ++mt) {
            bf16x8 ah[2], al[2];
            const int tS = (mt * 16 + (lane & 15)) ^ ((lane >> 4) << 3);
            #pragma unroll
            for (int kt = 0; kt < 2; ++kt) {
                const int cb = kt * 32 + (lane >> 4) * 8;
                float xf[8];
                #pragma unroll
                for (int j = 0; j < 8; ++j)
                    xf[j] = xs[wid * 2048 + (cb + j) * 32 + tS];
                #pragma unroll
                for (int j = 0; j < 8; ++j) {
                    short hb_ = f2bf(xf[j]);
                    ah[kt][j] = hb_;
                    al[kt][j] = f2bf(xf[j] - bf2f(hb_));
                }
            }
            const int row0 = mt * 16 + ((lane >> 4) << 2);
            #pragma unroll
            for (int nt = 0; nt < 6; ++nt) {
                const int g   = nt * 16 + (lane & 15);
                const int off = (g & 31) * 3 + (g >> 5);   // packed column
                const float bias = biasc[g];
                f32x4 acc = {bias, bias, bias, bias};
                bf16x8 b0 = *(const bf16x8*)(wfH + ((nt)     * 64 + lane) * 8);
                bf16x8 b1 = *(const bf16x8*)(wfH + ((6 + nt) * 64 + lane) * 8);
                acc = __builtin_amdgcn_mfma_f32_16x16x32_bf16(ah[0], b0, acc, 0, 0, 0);
                acc = __builtin_amdgcn_mfma_f32_16x16x32_bf16(ah[1], b1, acc, 0, 0, 0);
                acc = __builtin_amdgcn_mfma_f32_16x16x32_bf16(al[0], b0, acc, 0, 0, 0);
                acc = __builtin_amdgcn_mfma_f32_16x16x32_bf16(al[1], b1, acc, 0, 0, 0);
                b0 = *(const bf16x8*)(wfL + ((nt)     * 64 + lane) * 8);
                b1 = *(const bf16x8*)(wfL + ((6 + nt) * 64 + lane) * 8);
                acc = __builtin_amdgcn_mfma_f32_16x16x32_bf16(ah[0], b0, acc, 0, 0, 0);
                acc = __builtin_amdgcn_mfma_f32_16x16x32_bf16(ah[1], b1, acc, 0, 0, 0);
                // C layout: col = lane&15 (g), row = (lane>>4)*4 + reg (t)
                #pragma unroll
                for (int j = 0; j < 4; ++j)
                    gb[(row0 + j) * GXS + off] = acc[j];
            }
            if (mt == 0) __builtin_amdgcn_sched_barrier(0);  // cap reg pressure
        }
        // all xs reads drained -> safe to overwrite own xs region
        asm volatile("s_waitcnt lgkmcnt(0)" ::: "memory");
        if (prefetch_tile >= 0) load_xtile(prefetch_tile);
    };

    // consumer: 32 steps. Order per step: r/z matvec -> local sigmoid ->
    // shfl issued -> n-matvec executes UNDER the shfl -> tail.
    auto stage2 = [&](int buf) {
        const float* gb = gxs + buf * 12416 + (wid - 4) * 3104;
        __builtin_amdgcn_s_setprio(1);           // consumers own the SIMD
        float xr = gb[h3], xz = gb[h3 + 1], xn = gb[h3 + 2];   // s = 0
        #pragma unroll 2
        for (int s = 0; s < TT; ++s) {
            // prefetch step s+1 (independent of the h-chain)
            float xr_n = 0.f, xz_n = 0.f, xn_n = 0.f;
            if (s < TT - 1) {
                const float* nrow = gb + (s + 1) * GXS + h3;
                xr_n = nrow[0]; xz_n = nrow[1]; xn_n = nrow[2];
            }
            const int hb = __float_as_int(hout);
            // ---- r/z matvec (gate-split by half) ----
            float a0 = 0.f, a1 = 0.f, a2 = 0.f, a3 = 0.f;
            #pragma unroll
            for (int j = 0; j < 32; j += 4) {
                a0 = fmaf(wg_[j],     rlane(hb, j),     a0);
                a1 = fmaf(wg_[j + 1], rlane(hb, j + 1), a1);
                a2 = fmaf(wg_[j + 2], rlane(hb, j + 2), a2);
                a3 = fmaf(wg_[j + 3], rlane(hb, j + 3), a3);
            }
            float accA = (a0 + a1) + (a2 + a3);
            // joint sigmoid: half0 -> r, half1 -> z
            float xg  = (lane < 32) ? xr : xz;
            float sig = __builtin_amdgcn_rcpf(1.f + __expf(-(xg + accA)));
            float zs  = __shfl_xor(sig, 32, 64);     // in flight during aN
            __builtin_amdgcn_sched_barrier(0);       // pin: aN stays below shfl
            // ---- n matvec, hidden under the shfl latency ----
            float n0 = 0.f, n1 = 0.f, n2 = 0.f, n3 = 0.f;
            #pragma unroll
            for (int j = 0; j < 32; j += 4) {
                n0 = fmaf(wn_[j],     rlane(hb, j),     n0);
                n1 = fmaf(wn_[j + 1], rlane(hb, j + 1), n1);
                n2 = fmaf(wn_[j + 2], rlane(hb, j + 2), n2);
                n3 = fmaf(wn_[j + 3], rlane(hb, j + 3), n3);
            }
            float accN = (n0 + n1) + (n2 + n3);
            if (lane < 32) {
                float nx = fmaf(sig, accN + bhn, xn);   // sig == r on half0
                float n  = 1.f - 2.f * __builtin_amdgcn_rcpf(__expf(2.f * nx) + 1.f);
                hout = n + zs * (hout - n);          // lanes 0-31 hold h[0..31]
            }
            xr = xr_n; xz = xz_n; xn = xn_n;
        }
        __builtin_amdgcn_s_setprio(0);
    };

    // ================= pipeline =================
    if (wid < 4) load_xtile(0);
    __syncthreads();                    // wfrag+bias ready; xs = tile 0

    if (wid < 4) stage1(0, 1);          // gxs[0] = tile 0; prefetch tile 1
    __syncthreads();                    // gxs[0] visible; xs = tile 1

    for (int k = 0; k < 32; ++k) {
        if (wid >= 4) {
            stage2(k & 1);
        } else if (k < 31) {
            stage1((k + 1) & 1, (k < 30) ? (k + 2) : -1);
        }
        __syncthreads();
    }

    if (wid >= 4 && lane < 32)
        out[(bid * 4 + (wid - 4)) * 32 + h] = hout;
}

extern "C" void kernel_launch(void* const* d_in, const int* in_sizes, int n_in,
                              void* d_out, int out_size, void* d_ws, size_t ws_size,
                              hipStream_t stream) {
    const float* x    = (const float*)d_in[0];
    const float* W_ih = (const float*)d_in[1];
    const float* W_hh = (const float*)d_in[2];
    const float* b_ih = (const float*)d_in[3];
    const float* b_hh = (const float*)d_in[4];
    float* out = (float*)d_out;

    hipFuncSetAttribute((const void*)gru_fused14,
                        hipFuncAttributeMaxDynamicSharedMemorySize, LDS_BYTES);
    gru_fused14<<<256, 512, LDS_BYTES, stream>>>(x, W_ih, W_hh, b_ih, b_hh, out);
}

// Round 15
// 258.049 us; speedup vs baseline: 1.8793x; 1.0800x over previous
//
#include <hip/hip_runtime.h>

// GRU last-hidden: B=1024, C=64, T=1024, H=32, G=96, fp32.
// x:(B,64,1024) W_ih:(96,64) W_hh:(96,32) b_ih,b_hh:(96) out:(B,32)
//
// 256 blocks x 512 threads; block = 4 batches, 8 waves:
//   waves 0-3 = producers: gx tile via MFMA bf16 hi/lo (R9-squeezed, R11
//     xs swizzle — byte-identical to R11).
//   waves 4-7 = consumers: R11's verified single-loop gate-split matvec
//     (32 shared readlanes + pk_fma, joint sigmoid, ONE shfl). R15 cuts:
//       * gx prefetch DEPTH 2 (issue s+2 at s): ~500cy slack vs ~130, so
//         LDS-queue delays behind producer bursts stop landing on the chain
//       * branchless all-lane update: half1 uses r=zs (shuffled sig IS r
//         there) and its own sig as z -> no exec-mask toggle; hout valid on
//         all lanes (readlanes still 0-31; identical semantics)
//     (R14's split-loop shfl-hiding doubled readlanes -> reverted.)
//
// LDS (157056 B): unchanged from R11.

typedef short bf16x8 __attribute__((ext_vector_type(8)));
typedef float f32x4  __attribute__((ext_vector_type(4)));
typedef float f32x2  __attribute__((ext_vector_type(2)));

#define TT 32
#define GXS 97
#define LDS_BYTES 157056

#define GLL16(gp, lp)                                                        \
  __builtin_amdgcn_global_load_lds(                                          \
      (const __attribute__((address_space(1))) void*)(gp),                   \
      (__attribute__((address_space(3))) void*)(lp), 16, 0, 0)

static __device__ __forceinline__ short f2bf(float f) {   // RNE float->bf16
    unsigned u = __float_as_uint(f);
    u += 0x7fffu + ((u >> 16) & 1u);
    return (short)(u >> 16);
}
static __device__ __forceinline__ float bf2f(short s) {
    return __uint_as_float(((unsigned)(unsigned short)s) << 16);
}

__global__ __launch_bounds__(512) void gru_fused15(
    const float* __restrict__ x,
    const float* __restrict__ W_ih,
    const float* __restrict__ W_hh,
    const float* __restrict__ b_ih,
    const float* __restrict__ b_hh,
    float* __restrict__ out)
{
    extern __shared__ char smem[];
    short* wfH   = (short*)smem;                    // 768 frags * 8 shorts
    short* wfL   = (short*)(smem + 12288);
    float* xs    = (float*)(smem + 24576);          // 4 * 2048 floats
    float* gxs   = (float*)(smem + 57344);          // 2*4*32*97 floats
    float* biasc = (float*)(smem + 156672);         // 96 floats

    const int tid  = threadIdx.x;
    const int wid  = tid >> 6;
    const int lane = tid & 63;
    const int bid  = blockIdx.x;

    // ---- one-time: W_ih -> bf16 hi/lo MFMA B-fragments in LDS ----
    for (int f = tid; f < 768; f += 512) {
        int slot = f & 63, ktnt = f >> 6;
        int kt = ktnt / 6, nt = ktnt - kt * 6;
        int g  = nt * 16 + (slot & 15);
        int c0 = kt * 32 + (slot >> 4) * 8;
        const float* wr = W_ih + g * 64 + c0;
        bf16x8 hi, lo;
        #pragma unroll
        for (int j = 0; j < 8; ++j) {
            float v  = wr[j];
            short hb = f2bf(v);
            hi[j] = hb;
            lo[j] = f2bf(v - bf2f(hb));
        }
        *(bf16x8*)(wfH + f * 8) = hi;
        *(bf16x8*)(wfL + f * 8) = lo;
    }
    if (tid < 96) biasc[tid] = b_ih[tid] + (tid < 64 ? b_hh[tid] : 0.f);

    // ================= producer state =================
    const float* xb = nullptr;
    if (wid < 4) xb = x + (size_t)(bid * 4 + wid) * 64 * 1024;

    // ========== consumer state (gate-split, R8-verified layout) ==========
    const int h  = lane & 31;
    const int h3 = h * 3;
    f32x2 wg2[16], wn2[16];     // wg2: r-row (half0) / z-row (half1); wn2: n-row
    float bhn = 0.f, hout = 0.f;
    if (wid >= 4) {
        const int grow = (lane < 32) ? h : (32 + h);
        #pragma unroll
        for (int j = 0; j < 16; ++j) {
            wg2[j] = *(const f32x2*)(W_hh + grow * 32 + 2 * j);
            wn2[j] = *(const f32x2*)(W_hh + (64 + h) * 32 + 2 * j);
        }
        bhn = b_hh[64 + h];
    }

    // async x-tile: LDS[c][q] holds x[c][q ^ (((c>>3)&3)<<3)] (XOR applied
    // to the GLOBAL source t-offset; LDS dest stays linear).
    auto load_xtile = [&](int tile) {
        const int tbase = tile * TT;
        const int c_lo  = lane >> 3;
        #pragma unroll
        for (int i = 0; i < 8; ++i) {
            const int toff = (((lane & 7) << 2) ^ ((i & 3) << 3));
            const float* gp = xb + (i * 8 + c_lo) * 1024 + tbase + toff;
            float* lp = xs + wid * 2048 + i * 256;   // wave-uniform base
            GLL16(gp, lp);
        }
    };

    // producer: gx tile via MFMA, mt-at-a-time, paired B-frags, bias from LDS
    auto stage1 = [&](int buf, int prefetch_tile) {
        float* gb = gxs + buf * 12416 + wid * 3104;
        #pragma unroll
        for (int mt = 0; mt < 2; ++mt) {
            bf16x8 ah[2], al[2];
            const int tS = (mt * 16 + (lane & 15)) ^ ((lane >> 4) << 3);
            #pragma unroll
            for (int kt = 0; kt < 2; ++kt) {
                const int cb = kt * 32 + (lane >> 4) * 8;
                float xf[8];
                #pragma unroll
                for (int j = 0; j < 8; ++j)
                    xf[j] = xs[wid * 2048 + (cb + j) * 32 + tS];
                #pragma unroll
                for (int j = 0; j < 8; ++j) {
                    short hb_ = f2bf(xf[j]);
                    ah[kt][j] = hb_;
                    al[kt][j] = f2bf(xf[j] - bf2f(hb_));
                }
            }
            const int row0 = mt * 16 + ((lane >> 4) << 2);
            #pragma unroll
            for (int nt = 0; nt < 6; ++nt) {
                const int g   = nt * 16 + (lane & 15);
                const int off = (g & 31) * 3 + (g >> 5);   // packed column
                const float bias = biasc[g];
                f32x4 acc = {bias, bias, bias, bias};
                bf16x8 b0 = *(const bf16x8*)(wfH + ((nt)     * 64 + lane) * 8);
                bf16x8 b1 = *(const bf16x8*)(wfH + ((6 + nt) * 64 + lane) * 8);
                acc = __builtin_amdgcn_mfma_f32_16x16x32_bf16(ah[0], b0, acc, 0, 0, 0);
                acc = __builtin_amdgcn_mfma_f32_16x16x32_bf16(ah[1], b1, acc, 0, 0, 0);
                acc = __builtin_amdgcn_mfma_f32_16x16x32_bf16(al[0], b0, acc, 0, 0, 0);
                acc = __builtin_amdgcn_mfma_f32_16x16x32_bf16(al[1], b1, acc, 0, 0, 0);
                b0 = *(const bf16x8*)(wfL + ((nt)     * 64 + lane) * 8);
                b1 = *(const bf16x8*)(wfL + ((6 + nt) * 64 + lane) * 8);
                acc = __builtin_amdgcn_mfma_f32_16x16x32_bf16(ah[0], b0, acc, 0, 0, 0);
                acc = __builtin_amdgcn_mfma_f32_16x16x32_bf16(ah[1], b1, acc, 0, 0, 0);
                // C layout: col = lane&15 (g), row = (lane>>4)*4 + reg (t)
                #pragma unroll
                for (int j = 0; j < 4; ++j)
                    gb[(row0 + j) * GXS + off] = acc[j];
            }
            if (mt == 0) __builtin_amdgcn_sched_barrier(0);  // cap reg pressure
        }
        // all xs reads drained -> safe to overwrite own xs region
        asm volatile("s_waitcnt lgkmcnt(0)" ::: "memory");
        if (prefetch_tile >= 0) load_xtile(prefetch_tile);
    };

    // consumer: 32 steps; R11 single-loop matvec; gx prefetch depth 2;
    // branchless all-lane update (half1: r=zs, z=sig).
    auto stage2 = [&](int buf) {
        const float* gb = gxs + buf * 12416 + (wid - 4) * 3104;
        __builtin_amdgcn_s_setprio(1);           // consumers own the SIMD
        float xr0 = gb[h3],           xz0 = gb[h3 + 1],           xn0 = gb[h3 + 2];
        float xr1 = gb[GXS + h3],     xz1 = gb[GXS + h3 + 1],     xn1 = gb[GXS + h3 + 2];
        #pragma unroll 2
        for (int s = 0; s < TT; ++s) {
            // prefetch step s+2 (deep slack vs producer LDS bursts)
            float xr2 = 0.f, xz2 = 0.f, xn2 = 0.f;
            if (s < TT - 2) {
                const float* nrow = gb + (s + 2) * GXS + h3;
                xr2 = nrow[0]; xz2 = nrow[1]; xn2 = nrow[2];
            }
            f32x2 aA0 = {0.f, 0.f}, aA1 = {0.f, 0.f};
            f32x2 aN0 = {0.f, 0.f}, aN1 = {0.f, 0.f};
            const int hb = __float_as_int(hout);
            #pragma unroll
            for (int j = 0; j < 16; j += 2) {
                float s0 = __int_as_float(__builtin_amdgcn_readlane(hb, 2 * j));
                float s1 = __int_as_float(__builtin_amdgcn_readlane(hb, 2 * j + 1));
                float s2 = __int_as_float(__builtin_amdgcn_readlane(hb, 2 * j + 2));
                float s3 = __int_as_float(__builtin_amdgcn_readlane(hb, 2 * j + 3));
                f32x2 h01 = {s0, s1}, h23 = {s2, s3};
                aA0 = __builtin_elementwise_fma(wg2[j],     h01, aA0);
                aA1 = __builtin_elementwise_fma(wg2[j + 1], h23, aA1);
                aN0 = __builtin_elementwise_fma(wn2[j],     h01, aN0);
                aN1 = __builtin_elementwise_fma(wn2[j + 1], h23, aN1);
            }
            f32x2 aA = aA0 + aA1;
            f32x2 aN = aN0 + aN1;
            float accA = aA.x + aA.y;                // r-mv (half0) / z-mv (half1)
            float accN = aN.x + aN.y;                // n-mv (both halves)
            // joint sigmoid: half0 -> sig=r, half1 -> sig=z
            float xg  = (lane < 32) ? xr0 : xz0;
            float sig = __builtin_amdgcn_rcpf(1.f + __expf(-(xg + accA)));
            float zs  = __shfl_xor(sig, 32, 64);     // other half's sigmoid
            // branchless all-lane update: r/z selected per half
            float rv = (lane < 32) ? sig : zs;
            float zv = (lane < 32) ? zs  : sig;
            float nx = fmaf(rv, accN + bhn, xn0);
            float n  = 1.f - 2.f * __builtin_amdgcn_rcpf(__expf(2.f * nx) + 1.f);
            hout = n + zv * (hout - n);              // valid on ALL lanes
            xr0 = xr1; xz0 = xz1; xn0 = xn1;
            xr1 = xr2; xz1 = xz2; xn1 = xn2;
        }
        __builtin_amdgcn_s_setprio(0);
    };

    // ================= pipeline =================
    if (wid < 4) load_xtile(0);
    __syncthreads();                    // wfrag+bias ready; xs = tile 0

    if (wid < 4) stage1(0, 1);          // gxs[0] = tile 0; prefetch tile 1
    __syncthreads();                    // gxs[0] visible; xs = tile 1

    for (int k = 0; k < 32; ++k) {
        if (wid >= 4) {
            stage2(k & 1);
        } else if (k < 31) {
            stage1((k + 1) & 1, (k < 30) ? (k + 2) : -1);
        }
        __syncthreads();
    }

    if (wid >= 4 && lane < 32)
        out[(bid * 4 + (wid - 4)) * 32 + h] = hout;
}

extern "C" void kernel_launch(void* const* d_in, const int* in_sizes, int n_in,
                              void* d_out, int out_size, void* d_ws, size_t ws_size,
                              hipStream_t stream) {
    const float* x    = (const float*)d_in[0];
    const float* W_ih = (const float*)d_in[1];
    const float* W_hh = (const float*)d_in[2];
    const float* b_ih = (const float*)d_in[3];
    const float* b_hh = (const float*)d_in[4];
    float* out = (float*)d_out;

    hipFuncSetAttribute((const void*)gru_fused15,
                        hipFuncAttributeMaxDynamicSharedMemorySize, LDS_BYTES);
    gru_fused15<<<256, 512, LDS_BYTES, stream>>>(x, W_ih, W_hh, b_ih, b_hh, out);
}

// Round 16
// 247.679 us; speedup vs baseline: 1.9579x; 1.0419x over previous
//
#include <hip/hip_runtime.h>

// GRU last-hidden: B=1024, C=64, T=1024, H=32, G=96, fp32.
// x:(B,64,1024) W_ih:(96,64) W_hh:(96,32) b_ih,b_hh:(96) out:(B,32)
//
// 256 blocks x 512 threads; block = 4 batches, 8 waves:
//   waves 0-3 = producers: gx tile via MFMA bf16 hi/lo 3-product (R9/R11
//     form) — R16: W_ih frags & bias PRE-SCALED per gate (r/z rows by
//     -log2(e), n rows by 2*log2(e); scaling applied BEFORE the hi/lo split,
//     so 3-product precision is unchanged). gxs therefore holds scaled gx.
//   waves 4-7 = consumers: R11/R15-verified gate-split recurrence. R16 issue
//     cuts (R13 showed the step is ~pure issue, not stalls):
//       * FULL unroll of the 32-step loop -> gx ds_reads use compile-time
//         offset: immediates (max 12KB < 64KB), no loop/address overhead
//       * exp2-form gates (weights pre-scaled at load): sigmoid =
//         rcp(1+exp2(v)), tanh = 1-2*rcp(exp2(u)+1) -> no muls on the
//         transcendental chain
//
// LDS (157056 B): unchanged from R11.

typedef short bf16x8 __attribute__((ext_vector_type(8)));
typedef float f32x4  __attribute__((ext_vector_type(4)));
typedef float f32x2  __attribute__((ext_vector_type(2)));

#define TT 32
#define GXS 97
#define LDS_BYTES 157056
#define NLOG2E -1.44269504088896340736f   // -log2(e)
#define P2LOG2E 2.88539008177792681472f   // +2*log2(e)

#define GLL16(gp, lp)                                                        \
  __builtin_amdgcn_global_load_lds(                                          \
      (const __attribute__((address_space(1))) void*)(gp),                   \
      (__attribute__((address_space(3))) void*)(lp), 16, 0, 0)

static __device__ __forceinline__ short f2bf(float f) {   // RNE float->bf16
    unsigned u = __float_as_uint(f);
    u += 0x7fffu + ((u >> 16) & 1u);
    return (short)(u >> 16);
}
static __device__ __forceinline__ float bf2f(short s) {
    return __uint_as_float(((unsigned)(unsigned short)s) << 16);
}

__global__ __launch_bounds__(512) void gru_fused16(
    const float* __restrict__ x,
    const float* __restrict__ W_ih,
    const float* __restrict__ W_hh,
    const float* __restrict__ b_ih,
    const float* __restrict__ b_hh,
    float* __restrict__ out)
{
    extern __shared__ char smem[];
    short* wfH   = (short*)smem;                    // 768 frags * 8 shorts
    short* wfL   = (short*)(smem + 12288);
    float* xs    = (float*)(smem + 24576);          // 4 * 2048 floats
    float* gxs   = (float*)(smem + 57344);          // 2*4*32*97 floats
    float* biasc = (float*)(smem + 156672);         // 96 floats

    const int tid  = threadIdx.x;
    const int wid  = tid >> 6;
    const int lane = tid & 63;
    const int bid  = blockIdx.x;

    // ---- one-time: W_ih (pre-scaled per gate) -> bf16 hi/lo B-frags ----
    for (int f = tid; f < 768; f += 512) {
        int slot = f & 63, ktnt = f >> 6;
        int kt = ktnt / 6, nt = ktnt - kt * 6;
        int g  = nt * 16 + (slot & 15);
        int c0 = kt * 32 + (slot >> 4) * 8;
        const float sc = (g < 64) ? NLOG2E : P2LOG2E;
        const float* wr = W_ih + g * 64 + c0;
        bf16x8 hi, lo;
        #pragma unroll
        for (int j = 0; j < 8; ++j) {
            float v  = wr[j] * sc;
            short hb = f2bf(v);
            hi[j] = hb;
            lo[j] = f2bf(v - bf2f(hb));
        }
        *(bf16x8*)(wfH + f * 8) = hi;
        *(bf16x8*)(wfL + f * 8) = lo;
    }
    if (tid < 96) {
        const float sc = (tid < 64) ? NLOG2E : P2LOG2E;
        biasc[tid] = (b_ih[tid] + (tid < 64 ? b_hh[tid] : 0.f)) * sc;
    }

    // ================= producer state =================
    const float* xb = nullptr;
    if (wid < 4) xb = x + (size_t)(bid * 4 + wid) * 64 * 1024;

    // ========== consumer state (gate-split, pre-scaled weights) ==========
    const int h  = lane & 31;
    const int h3 = h * 3;
    f32x2 wg2[16], wn2[16];     // wg2: r-row (half0) / z-row (half1); wn2: n-row
    float bhn = 0.f, hout = 0.f;
    if (wid >= 4) {
        const int grow = (lane < 32) ? h : (32 + h);
        #pragma unroll
        for (int j = 0; j < 16; ++j) {
            f32x2 a = *(const f32x2*)(W_hh + grow * 32 + 2 * j);
            f32x2 b = *(const f32x2*)(W_hh + (64 + h) * 32 + 2 * j);
            wg2[j].x = a.x * NLOG2E;  wg2[j].y = a.y * NLOG2E;
            wn2[j].x = b.x * P2LOG2E; wn2[j].y = b.y * P2LOG2E;
        }
        bhn = b_hh[64 + h] * P2LOG2E;
    }

    // async x-tile: LDS[c][q] holds x[c][q ^ (((c>>3)&3)<<3)] (XOR applied
    // to the GLOBAL source t-offset; LDS dest stays linear).
    auto load_xtile = [&](int tile) {
        const int tbase = tile * TT;
        const int c_lo  = lane >> 3;
        #pragma unroll
        for (int i = 0; i < 8; ++i) {
            const int toff = (((lane & 7) << 2) ^ ((i & 3) << 3));
            const float* gp = xb + (i * 8 + c_lo) * 1024 + tbase + toff;
            float* lp = xs + wid * 2048 + i * 256;   // wave-uniform base
            GLL16(gp, lp);
        }
    };

    // producer: gx tile via MFMA, mt-at-a-time, paired B-frags, bias from LDS
    auto stage1 = [&](int buf, int prefetch_tile) {
        float* gb = gxs + buf * 12416 + wid * 3104;
        #pragma unroll
        for (int mt = 0; mt < 2; ++mt) {
            bf16x8 ah[2], al[2];
            const int tS = (mt * 16 + (lane & 15)) ^ ((lane >> 4) << 3);
            #pragma unroll
            for (int kt = 0; kt < 2; ++kt) {
                const int cb = kt * 32 + (lane >> 4) * 8;
                float xf[8];
                #pragma unroll
                for (int j = 0; j < 8; ++j)
                    xf[j] = xs[wid * 2048 + (cb + j) * 32 + tS];
                #pragma unroll
                for (int j = 0; j < 8; ++j) {
                    short hb_ = f2bf(xf[j]);
                    ah[kt][j] = hb_;
                    al[kt][j] = f2bf(xf[j] - bf2f(hb_));
                }
            }
            const int row0 = mt * 16 + ((lane >> 4) << 2);
            #pragma unroll
            for (int nt = 0; nt < 6; ++nt) {
                const int g   = nt * 16 + (lane & 15);
                const int off = (g & 31) * 3 + (g >> 5);   // packed column
                const float bias = biasc[g];
                f32x4 acc = {bias, bias, bias, bias};
                bf16x8 b0 = *(const bf16x8*)(wfH + ((nt)     * 64 + lane) * 8);
                bf16x8 b1 = *(const bf16x8*)(wfH + ((6 + nt) * 64 + lane) * 8);
                acc = __builtin_amdgcn_mfma_f32_16x16x32_bf16(ah[0], b0, acc, 0, 0, 0);
                acc = __builtin_amdgcn_mfma_f32_16x16x32_bf16(ah[1], b1, acc, 0, 0, 0);
                acc = __builtin_amdgcn_mfma_f32_16x16x32_bf16(al[0], b0, acc, 0, 0, 0);
                acc = __builtin_amdgcn_mfma_f32_16x16x32_bf16(al[1], b1, acc, 0, 0, 0);
                b0 = *(const bf16x8*)(wfL + ((nt)     * 64 + lane) * 8);
                b1 = *(const bf16x8*)(wfL + ((6 + nt) * 64 + lane) * 8);
                acc = __builtin_amdgcn_mfma_f32_16x16x32_bf16(ah[0], b0, acc, 0, 0, 0);
                acc = __builtin_amdgcn_mfma_f32_16x16x32_bf16(ah[1], b1, acc, 0, 0, 0);
                // C layout: col = lane&15 (g), row = (lane>>4)*4 + reg (t)
                #pragma unroll
                for (int j = 0; j < 4; ++j)
                    gb[(row0 + j) * GXS + off] = acc[j];
            }
            if (mt == 0) __builtin_amdgcn_sched_barrier(0);  // cap reg pressure
        }
        // all xs reads drained -> safe to overwrite own xs region
        asm volatile("s_waitcnt lgkmcnt(0)" ::: "memory");
        if (prefetch_tile >= 0) load_xtile(prefetch_tile);
    };

    // consumer: 32 steps FULLY UNROLLED (immediate ds offsets); exp2 gates
    // on pre-scaled inputs; depth-2 gx prefetch; one shfl per step.
    auto stage2 = [&](int buf) {
        const float* gb = gxs + buf * 12416 + (wid - 4) * 3104 + h3;
        __builtin_amdgcn_s_setprio(1);           // consumers own the SIMD
        float xr0 = gb[0],       xz0 = gb[1],       xn0 = gb[2];
        float xr1 = gb[GXS],     xz1 = gb[GXS + 1], xn1 = gb[GXS + 2];
        #pragma unroll
        for (int s = 0; s < TT; ++s) {
            float xr2 = 0.f, xz2 = 0.f, xn2 = 0.f;
            if (s < TT - 2) {                    // static with full unroll
                const float* nrow = gb + (s + 2) * GXS;
                xr2 = nrow[0]; xz2 = nrow[1]; xn2 = nrow[2];
            }
            f32x2 aA0 = {0.f, 0.f}, aA1 = {0.f, 0.f};
            f32x2 aN0 = {0.f, 0.f}, aN1 = {0.f, 0.f};
            const int hb = __float_as_int(hout);
            #pragma unroll
            for (int j = 0; j < 16; j += 2) {
                float s0 = __int_as_float(__builtin_amdgcn_readlane(hb, 2 * j));
                float s1 = __int_as_float(__builtin_amdgcn_readlane(hb, 2 * j + 1));
                float s2 = __int_as_float(__builtin_amdgcn_readlane(hb, 2 * j + 2));
                float s3 = __int_as_float(__builtin_amdgcn_readlane(hb, 2 * j + 3));
                f32x2 h01 = {s0, s1}, h23 = {s2, s3};
                aA0 = __builtin_elementwise_fma(wg2[j],     h01, aA0);
                aA1 = __builtin_elementwise_fma(wg2[j + 1], h23, aA1);
                aN0 = __builtin_elementwise_fma(wn2[j],     h01, aN0);
                aN1 = __builtin_elementwise_fma(wn2[j + 1], h23, aN1);
            }
            f32x2 aA = aA0 + aA1;
            f32x2 aN = aN0 + aN1;
            float accA = aA.x + aA.y;                // scaled r/z matvec
            float accN = aN.x + aN.y;                // scaled n matvec
            // sigmoid on pre-scaled arg: sig = rcp(1 + exp2(v))
            float xg  = (lane < 32) ? xr0 : xz0;
            float sig = __builtin_amdgcn_rcpf(
                            1.f + __builtin_amdgcn_exp2f(xg + accA));
            float zs  = __shfl_xor(sig, 32, 64);     // other half's sigmoid
            float rv = (lane < 32) ? sig : zs;
            float zv = (lane < 32) ? zs  : sig;
            // tanh on pre-scaled arg: n = 1 - 2*rcp(exp2(u)+1)
            float u  = fmaf(rv, accN + bhn, xn0);
            float n  = fmaf(-2.f, __builtin_amdgcn_rcpf(
                                      __builtin_amdgcn_exp2f(u) + 1.f), 1.f);
            hout = n + zv * (hout - n);              // valid on ALL lanes
            xr0 = xr1; xz0 = xz1; xn0 = xn1;
            xr1 = xr2; xz1 = xz2; xn1 = xn2;
        }
        __builtin_amdgcn_s_setprio(0);
    };

    // ================= pipeline =================
    if (wid < 4) load_xtile(0);
    __syncthreads();                    // wfrag+bias ready; xs = tile 0

    if (wid < 4) stage1(0, 1);          // gxs[0] = tile 0; prefetch tile 1
    __syncthreads();                    // gxs[0] visible; xs = tile 1

    for (int k = 0; k < 32; ++k) {
        if (wid >= 4) {
            stage2(k & 1);
        } else if (k < 31) {
            stage1((k + 1) & 1, (k < 30) ? (k + 2) : -1);
        }
        __syncthreads();
    }

    if (wid >= 4 && lane < 32)
        out[(bid * 4 + (wid - 4)) * 32 + h] = hout;
}

extern "C" void kernel_launch(void* const* d_in, const int* in_sizes, int n_in,
                              void* d_out, int out_size, void* d_ws, size_t ws_size,
                              hipStream_t stream) {
    const float* x    = (const float*)d_in[0];
    const float* W_ih = (const float*)d_in[1];
    const float* W_hh = (const float*)d_in[2];
    const float* b_ih = (const float*)d_in[3];
    const float* b_hh = (const float*)d_in[4];
    float* out = (float*)d_out;

    hipFuncSetAttribute((const void*)gru_fused16,
                        hipFuncAttributeMaxDynamicSharedMemorySize, LDS_BYTES);
    gru_fused16<<<256, 512, LDS_BYTES, stream>>>(x, W_ih, W_hh, b_ih, b_hh, out);
}

// Round 17
// 245.793 us; speedup vs baseline: 1.9730x; 1.0077x over previous
//
#include <hip/hip_runtime.h>

// GRU last-hidden: B=1024, C=64, T=1024, H=32, G=96, fp32.
// x:(B,64,1024) W_ih:(96,64) W_hh:(96,32) b_ih,b_hh:(96) out:(B,32)
//
// 256 blocks x 512 threads; block = 4 batches, 8 waves:
//   waves 0-3 = producers: gx tile via MFMA bf16 hi/lo 3-product, W_ih/bias
//     PRE-SCALED per gate for exp2-form gates (R16, verified).
//   waves 4-7 = consumers: gate-split matvec (32 readlane + 32 pk_fma).
//     R17: ship accA (the raw matvec) across halves IMMEDIATELY after the
//     dot tree — the shfl's ~100cy ds_bpermute latency now overlaps the
//     whole sigmoid chain instead of trailing it. Each half then computes
//     BOTH sigmoids locally (+1 exp2 +1 rcp, cheap) and the xg/rv/zv
//     cndmask selects disappear. Update valid on all lanes.
//
// LDS (157056 B): unchanged from R11/R16.

typedef short bf16x8 __attribute__((ext_vector_type(8)));
typedef float f32x4  __attribute__((ext_vector_type(4)));
typedef float f32x2  __attribute__((ext_vector_type(2)));

#define TT 32
#define GXS 97
#define LDS_BYTES 157056
#define NLOG2E -1.44269504088896340736f   // -log2(e)
#define P2LOG2E 2.88539008177792681472f   // +2*log2(e)

#define GLL16(gp, lp)                                                        \
  __builtin_amdgcn_global_load_lds(                                          \
      (const __attribute__((address_space(1))) void*)(gp),                   \
      (__attribute__((address_space(3))) void*)(lp), 16, 0, 0)

static __device__ __forceinline__ short f2bf(float f) {   // RNE float->bf16
    unsigned u = __float_as_uint(f);
    u += 0x7fffu + ((u >> 16) & 1u);
    return (short)(u >> 16);
}
static __device__ __forceinline__ float bf2f(short s) {
    return __uint_as_float(((unsigned)(unsigned short)s) << 16);
}

__global__ __launch_bounds__(512) void gru_fused17(
    const float* __restrict__ x,
    const float* __restrict__ W_ih,
    const float* __restrict__ W_hh,
    const float* __restrict__ b_ih,
    const float* __restrict__ b_hh,
    float* __restrict__ out)
{
    extern __shared__ char smem[];
    short* wfH   = (short*)smem;                    // 768 frags * 8 shorts
    short* wfL   = (short*)(smem + 12288);
    float* xs    = (float*)(smem + 24576);          // 4 * 2048 floats
    float* gxs   = (float*)(smem + 57344);          // 2*4*32*97 floats
    float* biasc = (float*)(smem + 156672);         // 96 floats

    const int tid  = threadIdx.x;
    const int wid  = tid >> 6;
    const int lane = tid & 63;
    const int bid  = blockIdx.x;

    // ---- one-time: W_ih (pre-scaled per gate) -> bf16 hi/lo B-frags ----
    for (int f = tid; f < 768; f += 512) {
        int slot = f & 63, ktnt = f >> 6;
        int kt = ktnt / 6, nt = ktnt - kt * 6;
        int g  = nt * 16 + (slot & 15);
        int c0 = kt * 32 + (slot >> 4) * 8;
        const float sc = (g < 64) ? NLOG2E : P2LOG2E;
        const float* wr = W_ih + g * 64 + c0;
        bf16x8 hi, lo;
        #pragma unroll
        for (int j = 0; j < 8; ++j) {
            float v  = wr[j] * sc;
            short hb = f2bf(v);
            hi[j] = hb;
            lo[j] = f2bf(v - bf2f(hb));
        }
        *(bf16x8*)(wfH + f * 8) = hi;
        *(bf16x8*)(wfL + f * 8) = lo;
    }
    if (tid < 96) {
        const float sc = (tid < 64) ? NLOG2E : P2LOG2E;
        biasc[tid] = (b_ih[tid] + (tid < 64 ? b_hh[tid] : 0.f)) * sc;
    }

    // ================= producer state =================
    const float* xb = nullptr;
    if (wid < 4) xb = x + (size_t)(bid * 4 + wid) * 64 * 1024;

    // ========== consumer state (gate-split, pre-scaled weights) ==========
    const int h  = lane & 31;
    const int h3 = h * 3;
    f32x2 wg2[16], wn2[16];     // wg2: r-row (half0) / z-row (half1); wn2: n-row
    float bhn = 0.f, hout = 0.f;
    if (wid >= 4) {
        const int grow = (lane < 32) ? h : (32 + h);
        #pragma unroll
        for (int j = 0; j < 16; ++j) {
            f32x2 a = *(const f32x2*)(W_hh + grow * 32 + 2 * j);
            f32x2 b = *(const f32x2*)(W_hh + (64 + h) * 32 + 2 * j);
            wg2[j].x = a.x * NLOG2E;  wg2[j].y = a.y * NLOG2E;
            wn2[j].x = b.x * P2LOG2E; wn2[j].y = b.y * P2LOG2E;
        }
        bhn = b_hh[64 + h] * P2LOG2E;
    }

    // async x-tile: LDS[c][q] holds x[c][q ^ (((c>>3)&3)<<3)] (XOR applied
    // to the GLOBAL source t-offset; LDS dest stays linear).
    auto load_xtile = [&](int tile) {
        const int tbase = tile * TT;
        const int c_lo  = lane >> 3;
        #pragma unroll
        for (int i = 0; i < 8; ++i) {
            const int toff = (((lane & 7) << 2) ^ ((i & 3) << 3));
            const float* gp = xb + (i * 8 + c_lo) * 1024 + tbase + toff;
            float* lp = xs + wid * 2048 + i * 256;   // wave-uniform base
            GLL16(gp, lp);
        }
    };

    // producer: gx tile via MFMA, mt-at-a-time, paired B-frags, bias from LDS
    auto stage1 = [&](int buf, int prefetch_tile) {
        float* gb = gxs + buf * 12416 + wid * 3104;
        #pragma unroll
        for (int mt = 0; mt < 2; ++mt) {
            bf16x8 ah[2], al[2];
            const int tS = (mt * 16 + (lane & 15)) ^ ((lane >> 4) << 3);
            #pragma unroll
            for (int kt = 0; kt < 2; ++kt) {
                const int cb = kt * 32 + (lane >> 4) * 8;
                float xf[8];
                #pragma unroll
                for (int j = 0; j < 8; ++j)
                    xf[j] = xs[wid * 2048 + (cb + j) * 32 + tS];
                #pragma unroll
                for (int j = 0; j < 8; ++j) {
                    short hb_ = f2bf(xf[j]);
                    ah[kt][j] = hb_;
                    al[kt][j] = f2bf(xf[j] - bf2f(hb_));
                }
            }
            const int row0 = mt * 16 + ((lane >> 4) << 2);
            #pragma unroll
            for (int nt = 0; nt < 6; ++nt) {
                const int g   = nt * 16 + (lane & 15);
                const int off = (g & 31) * 3 + (g >> 5);   // packed column
                const float bias = biasc[g];
                f32x4 acc = {bias, bias, bias, bias};
                bf16x8 b0 = *(const bf16x8*)(wfH + ((nt)     * 64 + lane) * 8);
                bf16x8 b1 = *(const bf16x8*)(wfH + ((6 + nt) * 64 + lane) * 8);
                acc = __builtin_amdgcn_mfma_f32_16x16x32_bf16(ah[0], b0, acc, 0, 0, 0);
                acc = __builtin_amdgcn_mfma_f32_16x16x32_bf16(ah[1], b1, acc, 0, 0, 0);
                acc = __builtin_amdgcn_mfma_f32_16x16x32_bf16(al[0], b0, acc, 0, 0, 0);
                acc = __builtin_amdgcn_mfma_f32_16x16x32_bf16(al[1], b1, acc, 0, 0, 0);
                b0 = *(const bf16x8*)(wfL + ((nt)     * 64 + lane) * 8);
                b1 = *(const bf16x8*)(wfL + ((6 + nt) * 64 + lane) * 8);
                acc = __builtin_amdgcn_mfma_f32_16x16x32_bf16(ah[0], b0, acc, 0, 0, 0);
                acc = __builtin_amdgcn_mfma_f32_16x16x32_bf16(ah[1], b1, acc, 0, 0, 0);
                // C layout: col = lane&15 (g), row = (lane>>4)*4 + reg (t)
                #pragma unroll
                for (int j = 0; j < 4; ++j)
                    gb[(row0 + j) * GXS + off] = acc[j];
            }
            if (mt == 0) __builtin_amdgcn_sched_barrier(0);  // cap reg pressure
        }
        // all xs reads drained -> safe to overwrite own xs region
        asm volatile("s_waitcnt lgkmcnt(0)" ::: "memory");
        if (prefetch_tile >= 0) load_xtile(prefetch_tile);
    };

    // consumer: 32 steps fully unrolled; accA shipped across halves right
    // after the dot tree (shfl hides under the sigmoid chain); both halves
    // compute both sigmoids locally; exp2-form gates; depth-2 prefetch.
    auto stage2 = [&](int buf) {
        const float* gb = gxs + buf * 12416 + (wid - 4) * 3104 + h3;
        __builtin_amdgcn_s_setprio(1);           // consumers own the SIMD
        float xr0 = gb[0],       xz0 = gb[1],       xn0 = gb[2];
        float xr1 = gb[GXS],     xz1 = gb[GXS + 1], xn1 = gb[GXS + 2];
        #pragma unroll
        for (int s = 0; s < TT; ++s) {
            float xr2 = 0.f, xz2 = 0.f, xn2 = 0.f;
            if (s < TT - 2) {                    // static with full unroll
                const float* nrow = gb + (s + 2) * GXS;
                xr2 = nrow[0]; xz2 = nrow[1]; xn2 = nrow[2];
            }
            f32x2 aA0 = {0.f, 0.f}, aA1 = {0.f, 0.f};
            f32x2 aN0 = {0.f, 0.f}, aN1 = {0.f, 0.f};
            const int hb = __float_as_int(hout);
            #pragma unroll
            for (int j = 0; j < 16; j += 2) {
                float s0 = __int_as_float(__builtin_amdgcn_readlane(hb, 2 * j));
                float s1 = __int_as_float(__builtin_amdgcn_readlane(hb, 2 * j + 1));
                float s2 = __int_as_float(__builtin_amdgcn_readlane(hb, 2 * j + 2));
                float s3 = __int_as_float(__builtin_amdgcn_readlane(hb, 2 * j + 3));
                f32x2 h01 = {s0, s1}, h23 = {s2, s3};
                aA0 = __builtin_elementwise_fma(wg2[j],     h01, aA0);
                aA1 = __builtin_elementwise_fma(wg2[j + 1], h23, aA1);
                aN0 = __builtin_elementwise_fma(wn2[j],     h01, aN0);
                aN1 = __builtin_elementwise_fma(wn2[j + 1], h23, aN1);
            }
            f32x2 aA = aA0 + aA1;
            f32x2 aN = aN0 + aN1;
            float accA = aA.x + aA.y;                // r-mv (half0) / z-mv (half1)
            // ship the raw matvec NOW — latency hides under both sigmoids
            float accO = __shfl_xor(accA, 32, 64);   // other half's matvec
            float accN = aN.x + aN.y;                // n-mv (both halves)
            // both sigmoids locally (args pre-scaled by -log2e)
            float accR = (lane < 32) ? accA : accO;
            float accZ = (lane < 32) ? accO : accA;
            float r = __builtin_amdgcn_rcpf(
                          1.f + __builtin_amdgcn_exp2f(xr0 + accR));
            float z = __builtin_amdgcn_rcpf(
                          1.f + __builtin_amdgcn_exp2f(xz0 + accZ));
            // tanh on pre-scaled arg: n = 1 - 2*rcp(exp2(u)+1)
            float u  = fmaf(r, accN + bhn, xn0);
            float n  = fmaf(-2.f, __builtin_amdgcn_rcpf(
                                      __builtin_amdgcn_exp2f(u) + 1.f), 1.f);
            hout = n + z * (hout - n);               // valid on ALL lanes
            xr0 = xr1; xz0 = xz1; xn0 = xn1;
            xr1 = xr2; xz1 = xz2; xn1 = xn2;
        }
        __builtin_amdgcn_s_setprio(0);
    };

    // ================= pipeline =================
    if (wid < 4) load_xtile(0);
    __syncthreads();                    // wfrag+bias ready; xs = tile 0

    if (wid < 4) stage1(0, 1);          // gxs[0] = tile 0; prefetch tile 1
    __syncthreads();                    // gxs[0] visible; xs = tile 1

    for (int k = 0; k < 32; ++k) {
        if (wid >= 4) {
            stage2(k & 1);
        } else if (k < 31) {
            stage1((k + 1) & 1, (k < 30) ? (k + 2) : -1);
        }
        __syncthreads();
    }

    if (wid >= 4 && lane < 32)
        out[(bid * 4 + (wid - 4)) * 32 + h] = hout;
}

extern "C" void kernel_launch(void* const* d_in, const int* in_sizes, int n_in,
                              void* d_out, int out_size, void* d_ws, size_t ws_size,
                              hipStream_t stream) {
    const float* x    = (const float*)d_in[0];
    const float* W_ih = (const float*)d_in[1];
    const float* W_hh = (const float*)d_in[2];
    const float* b_ih = (const float*)d_in[3];
    const float* b_hh = (const float*)d_in[4];
    float* out = (float*)d_out;

    hipFuncSetAttribute((const void*)gru_fused17,
                        hipFuncAttributeMaxDynamicSharedMemorySize, LDS_BYTES);
    gru_fused17<<<256, 512, LDS_BYTES, stream>>>(x, W_ih, W_hh, b_ih, b_hh, out);
}

// Round 18
// 233.514 us; speedup vs baseline: 2.0767x; 1.0526x over previous
//
#include <hip/hip_runtime.h>

// GRU last-hidden: B=1024, C=64, T=1024, H=32, G=96, fp32.
// x:(B,64,1024) W_ih:(96,64) W_hh:(96,32) b_ih,b_hh:(96) out:(B,32)
//
// 256 blocks x 512 threads; block = 4 batches, 8 waves:
//   waves 0-3 = producers: gx tile via MFMA bf16 hi/lo 3-product, W_ih/bias
//     PRE-SCALED per gate for exp2-form gates (R16, verified).
//   waves 4-7 = consumers: R17-verified recurrence, ONE change:
//     R18: the cross-half matvec exchange uses v_permlane32_swap_b32 (VALU,
//     ~4-8cy) instead of __shfl_xor (ds_bpermute, ~100-120cy sitting exposed
//     on the serial chain — R17 showed only ~15 inst of independent work can
//     hide under it). Direction-convention-proof combine: with a=b=accA,
//     after the swap {a,b} = {lo-copy, hi-copy} in SOME order under either
//     convention, so accO = (a+b) - accA == accA[lane^32] regardless
//     (fp error ~1e-7, negligible vs 3.9e-3 margin).
//
// LDS (157056 B): unchanged from R11/R16.

typedef short bf16x8 __attribute__((ext_vector_type(8)));
typedef float f32x4  __attribute__((ext_vector_type(4)));
typedef float f32x2  __attribute__((ext_vector_type(2)));

#define TT 32
#define GXS 97
#define LDS_BYTES 157056
#define NLOG2E -1.44269504088896340736f   // -log2(e)
#define P2LOG2E 2.88539008177792681472f   // +2*log2(e)

#define GLL16(gp, lp)                                                        \
  __builtin_amdgcn_global_load_lds(                                          \
      (const __attribute__((address_space(1))) void*)(gp),                   \
      (__attribute__((address_space(3))) void*)(lp), 16, 0, 0)

static __device__ __forceinline__ short f2bf(float f) {   // RNE float->bf16
    unsigned u = __float_as_uint(f);
    u += 0x7fffu + ((u >> 16) & 1u);
    return (short)(u >> 16);
}
static __device__ __forceinline__ float bf2f(short s) {
    return __uint_as_float(((unsigned)(unsigned short)s) << 16);
}

__global__ __launch_bounds__(512) void gru_fused18(
    const float* __restrict__ x,
    const float* __restrict__ W_ih,
    const float* __restrict__ W_hh,
    const float* __restrict__ b_ih,
    const float* __restrict__ b_hh,
    float* __restrict__ out)
{
    extern __shared__ char smem[];
    short* wfH   = (short*)smem;                    // 768 frags * 8 shorts
    short* wfL   = (short*)(smem + 12288);
    float* xs    = (float*)(smem + 24576);          // 4 * 2048 floats
    float* gxs   = (float*)(smem + 57344);          // 2*4*32*97 floats
    float* biasc = (float*)(smem + 156672);         // 96 floats

    const int tid  = threadIdx.x;
    const int wid  = tid >> 6;
    const int lane = tid & 63;
    const int bid  = blockIdx.x;

    // ---- one-time: W_ih (pre-scaled per gate) -> bf16 hi/lo B-frags ----
    for (int f = tid; f < 768; f += 512) {
        int slot = f & 63, ktnt = f >> 6;
        int kt = ktnt / 6, nt = ktnt - kt * 6;
        int g  = nt * 16 + (slot & 15);
        int c0 = kt * 32 + (slot >> 4) * 8;
        const float sc = (g < 64) ? NLOG2E : P2LOG2E;
        const float* wr = W_ih + g * 64 + c0;
        bf16x8 hi, lo;
        #pragma unroll
        for (int j = 0; j < 8; ++j) {
            float v  = wr[j] * sc;
            short hb = f2bf(v);
            hi[j] = hb;
            lo[j] = f2bf(v - bf2f(hb));
        }
        *(bf16x8*)(wfH + f * 8) = hi;
        *(bf16x8*)(wfL + f * 8) = lo;
    }
    if (tid < 96) {
        const float sc = (tid < 64) ? NLOG2E : P2LOG2E;
        biasc[tid] = (b_ih[tid] + (tid < 64 ? b_hh[tid] : 0.f)) * sc;
    }

    // ================= producer state =================
    const float* xb = nullptr;
    if (wid < 4) xb = x + (size_t)(bid * 4 + wid) * 64 * 1024;

    // ========== consumer state (gate-split, pre-scaled weights) ==========
    const int h  = lane & 31;
    const int h3 = h * 3;
    f32x2 wg2[16], wn2[16];     // wg2: r-row (half0) / z-row (half1); wn2: n-row
    float bhn = 0.f, hout = 0.f;
    if (wid >= 4) {
        const int grow = (lane < 32) ? h : (32 + h);
        #pragma unroll
        for (int j = 0; j < 16; ++j) {
            f32x2 a = *(const f32x2*)(W_hh + grow * 32 + 2 * j);
            f32x2 b = *(const f32x2*)(W_hh + (64 + h) * 32 + 2 * j);
            wg2[j].x = a.x * NLOG2E;  wg2[j].y = a.y * NLOG2E;
            wn2[j].x = b.x * P2LOG2E; wn2[j].y = b.y * P2LOG2E;
        }
        bhn = b_hh[64 + h] * P2LOG2E;
    }

    // async x-tile: LDS[c][q] holds x[c][q ^ (((c>>3)&3)<<3)] (XOR applied
    // to the GLOBAL source t-offset; LDS dest stays linear).
    auto load_xtile = [&](int tile) {
        const int tbase = tile * TT;
        const int c_lo  = lane >> 3;
        #pragma unroll
        for (int i = 0; i < 8; ++i) {
            const int toff = (((lane & 7) << 2) ^ ((i & 3) << 3));
            const float* gp = xb + (i * 8 + c_lo) * 1024 + tbase + toff;
            float* lp = xs + wid * 2048 + i * 256;   // wave-uniform base
            GLL16(gp, lp);
        }
    };

    // producer: gx tile via MFMA, mt-at-a-time, paired B-frags, bias from LDS
    auto stage1 = [&](int buf, int prefetch_tile) {
        float* gb = gxs + buf * 12416 + wid * 3104;
        #pragma unroll
        for (int mt = 0; mt < 2; ++mt) {
            bf16x8 ah[2], al[2];
            const int tS = (mt * 16 + (lane & 15)) ^ ((lane >> 4) << 3);
            #pragma unroll
            for (int kt = 0; kt < 2; ++kt) {
                const int cb = kt * 32 + (lane >> 4) * 8;
                float xf[8];
                #pragma unroll
                for (int j = 0; j < 8; ++j)
                    xf[j] = xs[wid * 2048 + (cb + j) * 32 + tS];
                #pragma unroll
                for (int j = 0; j < 8; ++j) {
                    short hb_ = f2bf(xf[j]);
                    ah[kt][j] = hb_;
                    al[kt][j] = f2bf(xf[j] - bf2f(hb_));
                }
            }
            const int row0 = mt * 16 + ((lane >> 4) << 2);
            #pragma unroll
            for (int nt = 0; nt < 6; ++nt) {
                const int g   = nt * 16 + (lane & 15);
                const int off = (g & 31) * 3 + (g >> 5);   // packed column
                const float bias = biasc[g];
                f32x4 acc = {bias, bias, bias, bias};
                bf16x8 b0 = *(const bf16x8*)(wfH + ((nt)     * 64 + lane) * 8);
                bf16x8 b1 = *(const bf16x8*)(wfH + ((6 + nt) * 64 + lane) * 8);
                acc = __builtin_amdgcn_mfma_f32_16x16x32_bf16(ah[0], b0, acc, 0, 0, 0);
                acc = __builtin_amdgcn_mfma_f32_16x16x32_bf16(ah[1], b1, acc, 0, 0, 0);
                acc = __builtin_amdgcn_mfma_f32_16x16x32_bf16(al[0], b0, acc, 0, 0, 0);
                acc = __builtin_amdgcn_mfma_f32_16x16x32_bf16(al[1], b1, acc, 0, 0, 0);
                b0 = *(const bf16x8*)(wfL + ((nt)     * 64 + lane) * 8);
                b1 = *(const bf16x8*)(wfL + ((6 + nt) * 64 + lane) * 8);
                acc = __builtin_amdgcn_mfma_f32_16x16x32_bf16(ah[0], b0, acc, 0, 0, 0);
                acc = __builtin_amdgcn_mfma_f32_16x16x32_bf16(ah[1], b1, acc, 0, 0, 0);
                // C layout: col = lane&15 (g), row = (lane>>4)*4 + reg (t)
                #pragma unroll
                for (int j = 0; j < 4; ++j)
                    gb[(row0 + j) * GXS + off] = acc[j];
            }
            if (mt == 0) __builtin_amdgcn_sched_barrier(0);  // cap reg pressure
        }
        // all xs reads drained -> safe to overwrite own xs region
        asm volatile("s_waitcnt lgkmcnt(0)" ::: "memory");
        if (prefetch_tile >= 0) load_xtile(prefetch_tile);
    };

    // consumer: 32 steps fully unrolled; cross-half exchange via
    // v_permlane32_swap (VALU) with direction-proof (a+b)-accA combine;
    // both halves compute both sigmoids; exp2-form gates; depth-2 prefetch.
    auto stage2 = [&](int buf) {
        const float* gb = gxs + buf * 12416 + (wid - 4) * 3104 + h3;
        __builtin_amdgcn_s_setprio(1);           // consumers own the SIMD
        float xr0 = gb[0],       xz0 = gb[1],       xn0 = gb[2];
        float xr1 = gb[GXS],     xz1 = gb[GXS + 1], xn1 = gb[GXS + 2];
        #pragma unroll
        for (int s = 0; s < TT; ++s) {
            float xr2 = 0.f, xz2 = 0.f, xn2 = 0.f;
            if (s < TT - 2) {                    // static with full unroll
                const float* nrow = gb + (s + 2) * GXS;
                xr2 = nrow[0]; xz2 = nrow[1]; xn2 = nrow[2];
            }
            f32x2 aA0 = {0.f, 0.f}, aA1 = {0.f, 0.f};
            f32x2 aN0 = {0.f, 0.f}, aN1 = {0.f, 0.f};
            const int hb = __float_as_int(hout);
            #pragma unroll
            for (int j = 0; j < 16; j += 2) {
                float s0 = __int_as_float(__builtin_amdgcn_readlane(hb, 2 * j));
                float s1 = __int_as_float(__builtin_amdgcn_readlane(hb, 2 * j + 1));
                float s2 = __int_as_float(__builtin_amdgcn_readlane(hb, 2 * j + 2));
                float s3 = __int_as_float(__builtin_amdgcn_readlane(hb, 2 * j + 3));
                f32x2 h01 = {s0, s1}, h23 = {s2, s3};
                aA0 = __builtin_elementwise_fma(wg2[j],     h01, aA0);
                aA1 = __builtin_elementwise_fma(wg2[j + 1], h23, aA1);
                aN0 = __builtin_elementwise_fma(wn2[j],     h01, aN0);
                aN1 = __builtin_elementwise_fma(wn2[j + 1], h23, aN1);
            }
            f32x2 aA = aA0 + aA1;
            f32x2 aN = aN0 + aN1;
            float accA = aA.x + aA.y;                // r-mv (half0) / z-mv (half1)
            // VALU cross-half exchange: after swap, {swA,swB} are the lo-copy
            // and hi-copy in SOME order (either HW convention) ->
            // accO = (swA+swB) - accA == accA[lane^32].
            float swA = accA, swB = accA;
            asm volatile("v_permlane32_swap_b32 %0, %1"
                         : "+v"(swA), "+v"(swB));
            float accO = (swA + swB) - accA;
            float accN = aN.x + aN.y;                // n-mv (both halves)
            // both sigmoids locally (args pre-scaled by -log2e)
            float accR = (lane < 32) ? accA : accO;
            float accZ = (lane < 32) ? accO : accA;
            float r = __builtin_amdgcn_rcpf(
                          1.f + __builtin_amdgcn_exp2f(xr0 + accR));
            float z = __builtin_amdgcn_rcpf(
                          1.f + __builtin_amdgcn_exp2f(xz0 + accZ));
            // tanh on pre-scaled arg: n = 1 - 2*rcp(exp2(u)+1)
            float u  = fmaf(r, accN + bhn, xn0);
            float n  = fmaf(-2.f, __builtin_amdgcn_rcpf(
                                      __builtin_amdgcn_exp2f(u) + 1.f), 1.f);
            hout = n + z * (hout - n);               // valid on ALL lanes
            xr0 = xr1; xz0 = xz1; xn0 = xn1;
            xr1 = xr2; xz1 = xz2; xn1 = xn2;
        }
        __builtin_amdgcn_s_setprio(0);
    };

    // ================= pipeline =================
    if (wid < 4) load_xtile(0);
    __syncthreads();                    // wfrag+bias ready; xs = tile 0

    if (wid < 4) stage1(0, 1);          // gxs[0] = tile 0; prefetch tile 1
    __syncthreads();                    // gxs[0] visible; xs = tile 1

    for (int k = 0; k < 32; ++k) {
        if (wid >= 4) {
            stage2(k & 1);
        } else if (k < 31) {
            stage1((k + 1) & 1, (k < 30) ? (k + 2) : -1);
        }
        __syncthreads();
    }

    if (wid >= 4 && lane < 32)
        out[(bid * 4 + (wid - 4)) * 32 + h] = hout;
}

extern "C" void kernel_launch(void* const* d_in, const int* in_sizes, int n_in,
                              void* d_out, int out_size, void* d_ws, size_t ws_size,
                              hipStream_t stream) {
    const float* x    = (const float*)d_in[0];
    const float* W_ih = (const float*)d_in[1];
    const float* W_hh = (const float*)d_in[2];
    const float* b_ih = (const float*)d_in[3];
    const float* b_hh = (const float*)d_in[4];
    float* out = (float*)d_out;

    hipFuncSetAttribute((const void*)gru_fused18,
                        hipFuncAttributeMaxDynamicSharedMemorySize, LDS_BYTES);
    gru_fused18<<<256, 512, LDS_BYTES, stream>>>(x, W_ih, W_hh, b_ih, b_hh, out);
}

// Round 20
// 191.724 us; speedup vs baseline: 2.5294x; 1.2180x over previous
//
#include <hip/hip_runtime.h>

// GRU last-hidden: B=1024, C=64, T=1024, H=32, G=96, fp32.
// x:(B,64,1024) W_ih:(96,64) W_hh:(96,32) b_ih,b_hh:(96) out:(B,32)
//
// 256 blocks x 512 threads; block = 4 batches, 8 waves:
//   waves 0-3 = producers: gx tile via MFMA bf16 hi/lo 3-product, W_ih/bias
//     PRE-SCALED per gate for exp2-form gates (R16, verified; unchanged).
//   waves 4-7 = consumers. R19/R20 issue cuts on the R18-verified skeleton:
//     * h broadcast as f16 PAIRS: hnb = DPP-ror1(hout); hpk =
//       cvt_pkrtz(hout,hnb); 16 readlanes (was 32). DPP rotation direction
//       resolved by RUNTIME PROBE at init (R6/R7 lesson).
//     * matvec via v_dot2_f32_f16 (32 dot2; f16 weights = 32 VGPR, was 64).
//       f16 precision pre-validated by R12 (absmax unchanged 0.0039).
//     * finished sigmoid shipped via permlane32_swap ((a+b)-x combine).
//     * 2 ds_reads/step (own-gate x + xn), was 3.
//     R20: fix R19's compile error — cvt_pkrtz returns __fp16x2, not
//     _Float16x2; pack union gets a __fp16-typed member (same bit layout).
//
// LDS (157056 B): unchanged from R11/R16.

typedef short bf16x8 __attribute__((ext_vector_type(8)));
typedef float f32x4  __attribute__((ext_vector_type(4)));
typedef float f32x2  __attribute__((ext_vector_type(2)));
typedef _Float16 f16x2 __attribute__((ext_vector_type(2)));
typedef __fp16 fp16v2 __attribute__((ext_vector_type(2)));

#define TT 32
#define GXS 97
#define LDS_BYTES 157056
#define NLOG2E -1.44269504088896340736f   // -log2(e)
#define P2LOG2E 2.88539008177792681472f   // +2*log2(e)

#if __has_builtin(__builtin_amdgcn_fdot2)
#define HAVE_DOT2 1
#else
#define HAVE_DOT2 0
#endif

#define GLL16(gp, lp)                                                        \
  __builtin_amdgcn_global_load_lds(                                          \
      (const __attribute__((address_space(1))) void*)(gp),                   \
      (__attribute__((address_space(3))) void*)(lp), 16, 0, 0)

static __device__ __forceinline__ short f2bf(float f) {   // RNE float->bf16
    unsigned u = __float_as_uint(f);
    u += 0x7fffu + ((u >> 16) & 1u);
    return (short)(u >> 16);
}
static __device__ __forceinline__ float bf2f(short s) {
    return __uint_as_float(((unsigned)(unsigned short)s) << 16);
}
// row_ror:1 — rotate within 16-lane rows (direction resolved at runtime)
static __device__ __forceinline__ float ror1(float x) {
    return __int_as_float(__builtin_amdgcn_update_dpp(
        0, __float_as_int(x), 0x121, 0xf, 0xf, true));
}
union HPk { int i; f16x2 h; fp16v2 p; };

__global__ __launch_bounds__(512) void gru_fused20(
    const float* __restrict__ x,
    const float* __restrict__ W_ih,
    const float* __restrict__ W_hh,
    const float* __restrict__ b_ih,
    const float* __restrict__ b_hh,
    float* __restrict__ out)
{
    extern __shared__ char smem[];
    short* wfH   = (short*)smem;                    // 768 frags * 8 shorts
    short* wfL   = (short*)(smem + 12288);
    float* xs    = (float*)(smem + 24576);          // 4 * 2048 floats
    float* gxs   = (float*)(smem + 57344);          // 2*4*32*97 floats
    float* biasc = (float*)(smem + 156672);         // 96 floats

    const int tid  = threadIdx.x;
    const int wid  = tid >> 6;
    const int lane = tid & 63;
    const int bid  = blockIdx.x;

    // ---- one-time: W_ih (pre-scaled per gate) -> bf16 hi/lo B-frags ----
    for (int f = tid; f < 768; f += 512) {
        int slot = f & 63, ktnt = f >> 6;
        int kt = ktnt / 6, nt = ktnt - kt * 6;
        int g  = nt * 16 + (slot & 15);
        int c0 = kt * 32 + (slot >> 4) * 8;
        const float sc = (g < 64) ? NLOG2E : P2LOG2E;
        const float* wr = W_ih + g * 64 + c0;
        bf16x8 hi, lo;
        #pragma unroll
        for (int j = 0; j < 8; ++j) {
            float v  = wr[j] * sc;
            short hb = f2bf(v);
            hi[j] = hb;
            lo[j] = f2bf(v - bf2f(hb));
        }
        *(bf16x8*)(wfH + f * 8) = hi;
        *(bf16x8*)(wfL + f * 8) = lo;
    }
    if (tid < 96) {
        const float sc = (tid < 64) ? NLOG2E : P2LOG2E;
        biasc[tid] = (b_ih[tid] + (tid < 64 ? b_hh[tid] : 0.f)) * sc;
    }

    // ================= producer state =================
    const float* xb = nullptr;
    if (wid < 4) xb = x + (size_t)(bid * 4 + wid) * 64 * 1024;

    // ========== consumer state (gate-split, pre-scaled weights) ==========
    const int h  = lane & 31;
    const int h3 = h * 3;
    float bhn = 0.f, hout = 0.f;

    // --- DPP direction probe (uniform): does lane0 receive lane1 or lane15?
    const float rotF = ror1((float)(lane & 15));
    const bool dirPlus =
        (__builtin_amdgcn_readlane(__float_as_int(rotF), 0) ==
         __float_as_int(1.0f));

#if HAVE_DOT2
    f16x2 wgp[16], wnp[16];   // 32 VGPRs of f16 weight pairs
    if (wid >= 4) {
        const int grow = (lane < 32) ? h : (32 + h);
        #pragma unroll
        for (int j = 0; j < 16; ++j) {
            const int ke = 2 * j;
            const int ko = dirPlus ? (ke + 1)
                                   : ((ke & 16) | ((ke + 15) & 15));
            wgp[j][0] = (_Float16)(W_hh[grow * 32 + ke] * NLOG2E);
            wgp[j][1] = (_Float16)(W_hh[grow * 32 + ko] * NLOG2E);
            wnp[j][0] = (_Float16)(W_hh[(64 + h) * 32 + ke] * P2LOG2E);
            wnp[j][1] = (_Float16)(W_hh[(64 + h) * 32 + ko] * P2LOG2E);
        }
        bhn = b_hh[64 + h] * P2LOG2E;
    }
#else
    f32x2 wg2[16], wn2[16];
    if (wid >= 4) {
        const int grow = (lane < 32) ? h : (32 + h);
        #pragma unroll
        for (int j = 0; j < 16; ++j) {
            f32x2 a = *(const f32x2*)(W_hh + grow * 32 + 2 * j);
            f32x2 b = *(const f32x2*)(W_hh + (64 + h) * 32 + 2 * j);
            wg2[j].x = a.x * NLOG2E;  wg2[j].y = a.y * NLOG2E;
            wn2[j].x = b.x * P2LOG2E; wn2[j].y = b.y * P2LOG2E;
        }
        bhn = b_hh[64 + h] * P2LOG2E;
    }
#endif

    // async x-tile: LDS[c][q] holds x[c][q ^ (((c>>3)&3)<<3)] (XOR applied
    // to the GLOBAL source t-offset; LDS dest stays linear).
    auto load_xtile = [&](int tile) {
        const int tbase = tile * TT;
        const int c_lo  = lane >> 3;
        #pragma unroll
        for (int i = 0; i < 8; ++i) {
            const int toff = (((lane & 7) << 2) ^ ((i & 3) << 3));
            const float* gp = xb + (i * 8 + c_lo) * 1024 + tbase + toff;
            float* lp = xs + wid * 2048 + i * 256;   // wave-uniform base
            GLL16(gp, lp);
        }
    };

    // producer: gx tile via MFMA, mt-at-a-time, paired B-frags, bias from LDS
    auto stage1 = [&](int buf, int prefetch_tile) {
        float* gb = gxs + buf * 12416 + wid * 3104;
        #pragma unroll
        for (int mt = 0; mt < 2; ++mt) {
            bf16x8 ah[2], al[2];
            const int tS = (mt * 16 + (lane & 15)) ^ ((lane >> 4) << 3);
            #pragma unroll
            for (int kt = 0; kt < 2; ++kt) {
                const int cb = kt * 32 + (lane >> 4) * 8;
                float xf[8];
                #pragma unroll
                for (int j = 0; j < 8; ++j)
                    xf[j] = xs[wid * 2048 + (cb + j) * 32 + tS];
                #pragma unroll
                for (int j = 0; j < 8; ++j) {
                    short hb_ = f2bf(xf[j]);
                    ah[kt][j] = hb_;
                    al[kt][j] = f2bf(xf[j] - bf2f(hb_));
                }
            }
            const int row0 = mt * 16 + ((lane >> 4) << 2);
            #pragma unroll
            for (int nt = 0; nt < 6; ++nt) {
                const int g   = nt * 16 + (lane & 15);
                const int off = (g & 31) * 3 + (g >> 5);   // packed column
                const float bias = biasc[g];
                f32x4 acc = {bias, bias, bias, bias};
                bf16x8 b0 = *(const bf16x8*)(wfH + ((nt)     * 64 + lane) * 8);
                bf16x8 b1 = *(const bf16x8*)(wfH + ((6 + nt) * 64 + lane) * 8);
                acc = __builtin_amdgcn_mfma_f32_16x16x32_bf16(ah[0], b0, acc, 0, 0, 0);
                acc = __builtin_amdgcn_mfma_f32_16x16x32_bf16(ah[1], b1, acc, 0, 0, 0);
                acc = __builtin_amdgcn_mfma_f32_16x16x32_bf16(al[0], b0, acc, 0, 0, 0);
                acc = __builtin_amdgcn_mfma_f32_16x16x32_bf16(al[1], b1, acc, 0, 0, 0);
                b0 = *(const bf16x8*)(wfL + ((nt)     * 64 + lane) * 8);
                b1 = *(const bf16x8*)(wfL + ((6 + nt) * 64 + lane) * 8);
                acc = __builtin_amdgcn_mfma_f32_16x16x32_bf16(ah[0], b0, acc, 0, 0, 0);
                acc = __builtin_amdgcn_mfma_f32_16x16x32_bf16(ah[1], b1, acc, 0, 0, 0);
                // C layout: col = lane&15 (g), row = (lane>>4)*4 + reg (t)
                #pragma unroll
                for (int j = 0; j < 4; ++j)
                    gb[(row0 + j) * GXS + off] = acc[j];
            }
            if (mt == 0) __builtin_amdgcn_sched_barrier(0);  // cap reg pressure
        }
        // all xs reads drained -> safe to overwrite own xs region
        asm volatile("s_waitcnt lgkmcnt(0)" ::: "memory");
        if (prefetch_tile >= 0) load_xtile(prefetch_tile);
    };

    // consumer: 32 steps fully unrolled. f16-pair broadcast (16 readlane) +
    // 32 dot2; finished sigmoid shipped via permlane; 2 ds_reads/step.
    auto stage2 = [&](int buf) {
        const float* gb = gxs + buf * 12416 + (wid - 4) * 3104 + h3;
        const int sel = (lane >> 5) & 1;    // 0: xr (half0), 1: xz (half1)
        __builtin_amdgcn_s_setprio(1);      // consumers own the SIMD
        float xg0 = gb[sel],       xn0 = gb[2];
        float xg1 = gb[GXS + sel], xn1 = gb[GXS + 2];
        #pragma unroll
        for (int s = 0; s < TT; ++s) {
            float xg2 = 0.f, xn2 = 0.f;
            if (s < TT - 2) {               // static with full unroll
                xg2 = gb[(s + 2) * GXS + sel];
                xn2 = gb[(s + 2) * GXS + 2];
            }
            float aA0 = 0.f, aA1 = 0.f, aN0 = 0.f, aN1 = 0.f;
#if HAVE_DOT2
            // pack own h with rotated neighbor -> even lane 2i holds
            // (h[2i], h[pair(2i)]) as f16x2; broadcast 16 packs
            HPk hp; hp.p = __builtin_amdgcn_cvt_pkrtz(hout, ror1(hout));
            const int hpb = hp.i;
            #pragma unroll
            for (int j = 0; j < 16; j += 2) {
                HPk p0; p0.i = __builtin_amdgcn_readlane(hpb, 2 * j);
                HPk p1; p1.i = __builtin_amdgcn_readlane(hpb, 2 * j + 2);
                aA0 = __builtin_amdgcn_fdot2(wgp[j],     p0.h, aA0, false);
                aA1 = __builtin_amdgcn_fdot2(wgp[j + 1], p1.h, aA1, false);
                aN0 = __builtin_amdgcn_fdot2(wnp[j],     p0.h, aN0, false);
                aN1 = __builtin_amdgcn_fdot2(wnp[j + 1], p1.h, aN1, false);
            }
            float accA = aA0 + aA1;
            float accN = aN0 + aN1;
#else
            f32x2 vA0 = {0.f, 0.f}, vA1 = {0.f, 0.f};
            f32x2 vN0 = {0.f, 0.f}, vN1 = {0.f, 0.f};
            const int hb = __float_as_int(hout);
            #pragma unroll
            for (int j = 0; j < 16; j += 2) {
                float s0 = __int_as_float(__builtin_amdgcn_readlane(hb, 2 * j));
                float s1 = __int_as_float(__builtin_amdgcn_readlane(hb, 2 * j + 1));
                float s2 = __int_as_float(__builtin_amdgcn_readlane(hb, 2 * j + 2));
                float s3 = __int_as_float(__builtin_amdgcn_readlane(hb, 2 * j + 3));
                f32x2 h01 = {s0, s1}, h23 = {s2, s3};
                vA0 = __builtin_elementwise_fma(wg2[j],     h01, vA0);
                vA1 = __builtin_elementwise_fma(wg2[j + 1], h23, vA1);
                vN0 = __builtin_elementwise_fma(wn2[j],     h01, vN0);
                vN1 = __builtin_elementwise_fma(wn2[j + 1], h23, vN1);
            }
            f32x2 vA = vA0 + vA1, vN = vN0 + vN1;
            float accA = vA.x + vA.y;
            float accN = vN.x + vN.y;
#endif
            // own-gate sigmoid, then ship the FINISHED sigmoid (VALU swap)
            float sig = __builtin_amdgcn_rcpf(
                            1.f + __builtin_amdgcn_exp2f(xg0 + accA));
            float swA = sig, swB = sig;
            asm volatile("v_permlane32_swap_b32 %0, %1"
                         : "+v"(swA), "+v"(swB));
            float oth = (swA + swB) - sig;       // other half's sigmoid
            float r = (lane < 32) ? sig : oth;
            float z = (lane < 32) ? oth : sig;
            // tanh on pre-scaled arg: n = 1 - 2*rcp(exp2(u)+1)
            float u  = fmaf(r, accN + bhn, xn0);
            float n  = fmaf(-2.f, __builtin_amdgcn_rcpf(
                                      __builtin_amdgcn_exp2f(u) + 1.f), 1.f);
            hout = n + z * (hout - n);           // valid on ALL lanes
            xg0 = xg1; xn0 = xn1;
            xg1 = xg2; xn1 = xn2;
        }
        __builtin_amdgcn_s_setprio(0);
    };

    // ================= pipeline =================
    if (wid < 4) load_xtile(0);
    __syncthreads();                    // wfrag+bias ready; xs = tile 0

    if (wid < 4) stage1(0, 1);          // gxs[0] = tile 0; prefetch tile 1
    __syncthreads();                    // gxs[0] visible; xs = tile 1

    for (int k = 0; k < 32; ++k) {
        if (wid >= 4) {
            stage2(k & 1);
        } else if (k < 31) {
            stage1((k + 1) & 1, (k < 30) ? (k + 2) : -1);
        }
        __syncthreads();
    }

    if (wid >= 4 && lane < 32)
        out[(bid * 4 + (wid - 4)) * 32 + h] = hout;
}

extern "C" void kernel_launch(void* const* d_in, const int* in_sizes, int n_in,
                              void* d_out, int out_size, void* d_ws, size_t ws_size,
                              hipStream_t stream) {
    const float* x    = (const float*)d_in[0];
    const float* W_ih = (const float*)d_in[1];
    const float* W_hh = (const float*)d_in[2];
    const float* b_ih = (const float*)d_in[3];
    const float* b_hh = (const float*)d_in[4];
    float* out = (float*)d_out;

    hipFuncSetAttribute((const void*)gru_fused20,
                        hipFuncAttributeMaxDynamicSharedMemorySize, LDS_BYTES);
    gru_fused20<<<256, 512, LDS_BYTES, stream>>>(x, W_ih, W_hh, b_ih, b_hh, out);
}